// Round 4
// baseline (108.704 us; speedup 1.0000x reference)
//
#include <hip/hip_runtime.h>

#define NRAYS 2048
#define NS    128
#define G     128
#define FC    128
#define APPC  27
#define TILE  16
#define R1    351   // compact item-dependent rows: 27 feats + 162 sin + 162 cos

// W1 row map for compact row r: r<27 -> r (feats); r in [27,189) -> sin rows 30..191;
// r in [189,351) -> cos rows 192..353. i.e. k = r<27 ? r : r+3.
// Ray-constant rows (27..29 vd, 354..389 PE(vd)) + b1 live in s_hbase.

static __device__ __forceinline__ float tri_sample(const float* __restrict__ vol,
                                                   float gx, float gy, float gz) {
  int x0 = (int)gx; x0 = x0 < 0 ? 0 : (x0 > G - 2 ? G - 2 : x0);
  int y0 = (int)gy; y0 = y0 < 0 ? 0 : (y0 > G - 2 ? G - 2 : y0);
  int z0 = (int)gz; z0 = z0 < 0 ? 0 : (z0 > G - 2 ? G - 2 : z0);
  float fx = gx - (float)x0;
  float fy = gy - (float)y0;
  float fz = gz - (float)z0;
  const float* p = vol + ((z0 * G + y0) * G + x0);
  float v000 = p[0], v001 = p[1];
  float v010 = p[G], v011 = p[G + 1];
  const float* q = p + G * G;
  float v100 = q[0], v101 = q[1];
  float v110 = q[G], v111 = q[G + 1];
  float c00 = v000 + (v001 - v000) * fx;
  float c01 = v010 + (v011 - v010) * fx;
  float c10 = v100 + (v101 - v100) * fx;
  float c11 = v110 + (v111 - v110) * fx;
  float c0  = c00 + (c01 - c00) * fy;
  float c1  = c10 + (c11 - c10) * fy;
  return c0 + (c1 - c0) * fz;
}

__global__ __launch_bounds__(256) void k_all(const float* __restrict__ rays_o,
                                             const float* __restrict__ rays_d,
                                             const float* __restrict__ dgrid,
                                             const float* __restrict__ agrid,
                                             const float* __restrict__ W1,
                                             const float* __restrict__ W2,
                                             const float* __restrict__ W3,
                                             const float* __restrict__ b1,
                                             const float* __restrict__ b2,
                                             const float* __restrict__ b3,
                                             float* __restrict__ out) {
  const int ray  = blockIdx.x;
  const int tid  = threadIdx.x;
  const int lane = tid & 63;
  const int wid  = tid >> 6;

  __shared__ float s_inT[R1][TILE];   // 22464 B; tail-reused as h2 [128][20]
  __shared__ float s_hT[FC][20];      // 10240 B; fast path uses it flat
  __shared__ float s_wt[NS];
  __shared__ int   s_items[NS];
  __shared__ float s_hbase[FC];
  __shared__ float s_pevd[36];
  __shared__ float s_red[8];
  __shared__ int   s_cnt[2];
  __shared__ float s_gx[TILE], s_gy[TILE], s_gz[TILE], s_jw[TILE];
  __shared__ int   s_vld[TILE];
  __shared__ float s_rgbw[TILE][3];
  __shared__ float s_out[3];

  // redundant per-thread ray setup (broadcast loads, no barrier needed)
  const float rdx = rays_d[ray * 3 + 0], rdy = rays_d[ray * 3 + 1], rdz = rays_d[ray * 3 + 2];
  const float inv = rsqrtf(rdx * rdx + rdy * rdy + rdz * rdz);
  const float dx = rdx * inv, dy = rdy * inv, dz = rdz * inv;
  const float ox = rays_o[ray * 3 + 0], oy = rays_o[ray * 3 + 1], oz = rays_o[ray * 3 + 2];

  if (tid >= 192 && tid < 210) {   // waves 2-3 idle during scan: do PE(vd)
    const int i = tid - 192, d = i / 6, f = i % 6;
    const float vv = (d == 0) ? dx : ((d == 1) ? dy : dz);
    float sn, cs; __sincosf(vv * (float)(1 << f), &sn, &cs);
    s_pevd[i] = sn; s_pevd[18 + i] = cs;
  }
  if (tid < 3) s_out[tid] = 0.0f;

  // ---- alphas + per-wave inclusive product scan ----
  float alpha = 0.0f, incl = 1.0f;
  bool inb = false;
  unsigned long long m = 0ull;
  if (tid < NS) {
    const float t  = 2.0f + (4.0f / 127.0f) * (float)tid;
    const float px = (ox + dx * t) * (2.0f / 3.0f);
    const float py = (oy + dy * t) * (2.0f / 3.0f);
    const float pz = (oz + dz * t) * (2.0f / 3.0f);
    inb = (fabsf(px) <= 1.0f) && (fabsf(py) <= 1.0f) && (fabsf(pz) <= 1.0f);
    float sf = 0.0f;
    if (inb)
      sf = tri_sample(dgrid, (px + 1.0f) * 63.5f, (py + 1.0f) * 63.5f, (pz + 1.0f) * 63.5f);
    const float sigma = log1pf(__expf(sf - 10.0f));
    alpha = 1.0f - __expf(-sigma * 0.78125f);
    float p = 1.0f - alpha + 1e-10f;
    incl = p;
#pragma unroll
    for (int off = 1; off < 64; off <<= 1) {
      float v = __shfl_up(incl, off);
      if (lane >= off) incl *= v;
    }
    m = __ballot(inb);
    if (lane == 0) s_cnt[wid] = (int)__popcll(m);
    if (tid == 63) s_red[0] = incl;   // wave-0 total product
  }
  __syncthreads();  // B1

  const int n_in = s_cnt[0] + s_cnt[1];

  if (tid < NS) {
    float excl = __shfl_up(incl, 1);
    if (lane == 0) excl = 1.0f;
    const float T = excl * ((wid == 1) ? s_red[0] : 1.0f);
    const float w = alpha * T;
    s_wt[tid] = w;
    if (inb) {
      const int rank = (int)__popcll(m & ((1ull << lane) - 1ull));
      s_items[(wid ? s_cnt[0] : 0) + rank] = tid;
    }
    float sa = w, so = inb ? 0.0f : w;
#pragma unroll
    for (int off = 32; off > 0; off >>= 1) {
      sa += __shfl_xor(sa, off);
      so += __shfl_xor(so, off);
    }
    if (lane == 0) { s_red[2 + wid] = sa; s_red[4 + wid] = so; }
  }

  // hbase[n] = b1 + vd rows + PE(vd) rows  (shared by both paths)
  if (tid < FC) {
    float a = b1[tid];
    a = fmaf(dx, W1[27 * FC + tid], a);
    a = fmaf(dy, W1[28 * FC + tid], a);
    a = fmaf(dz, W1[29 * FC + tid], a);
#pragma unroll
    for (int k = 0; k < 36; ++k)
      a = fmaf(s_pevd[k], W1[(354 + k) * FC + tid], a);
    s_hbase[tid] = a;
  }
  __syncthreads();  // B2

  const float acc  = s_red[2] + s_red[3];
  const float woob = s_red[4] + s_red[5];

  float* sf_ = &s_hT[0][0];  // fast-path flat scratch (2560 floats available)

  // ================= fast path: no in-bounds samples =================
  if (n_in == 0) {
    if (tid < FC) {
      float a = s_hbase[tid];
#pragma unroll 8
      for (int k = 192; k < 354; ++k) a += W1[k * FC + tid];  // cos(0)=1 block
      sf_[tid] = fmaxf(a, 0.0f);
    }
    __syncthreads();
    {
      const int nrn = tid & 127, h = tid >> 7, k0 = h * 64;
      float c = 0.0f;
#pragma unroll 8
      for (int kk = 0; kk < 64; ++kk)
        c = fmaf(sf_[k0 + kk], W2[(k0 + kk) * FC + nrn], c);
      sf_[128 + h * 128 + nrn] = c;
    }
    __syncthreads();
    if (tid < FC)
      sf_[384 + tid] = fmaxf(sf_[128 + tid] + sf_[256 + tid] + b2[tid], 0.0f);
    __syncthreads();
    if (tid < 24) {
      const int p = tid / 3, c = tid - p * 3;
      float a3 = 0.0f;
#pragma unroll
      for (int kk = 0; kk < 16; ++kk)
        a3 = fmaf(sf_[384 + p * 16 + kk], W3[(p * 16 + kk) * 3 + c], a3);
      sf_[512 + tid] = a3;
    }
    __syncthreads();
    if (tid < 3) {
      float a3 = b3[tid];
#pragma unroll
      for (int p = 0; p < 8; ++p) a3 += sf_[512 + p * 3 + tid];
      const float rgb = 1.0f / (1.0f + __expf(-a3));
      const float val = woob * rgb + (1.0f - acc);
      out[ray * 3 + tid] = fminf(fmaxf(val, 0.0f), 1.0f);
    }
    return;
  }

  // ================= mixed path: batched MLP, item 0 = virtual OOB =================
  const int n_items = n_in + 1;
  for (int base = 0; base < n_items; base += TILE) {
    const int nt = (n_items - base < TILE) ? (n_items - base) : TILE;

    if (tid < TILE) {
      const int j = tid, gi = base + j;
      float wj = 0.0f, gx = 0.0f, gy = 0.0f, gz = 0.0f;
      int vld = 0;
      if (j < nt) {
        if (gi == 0) {
          wj = woob;  // feats stay 0 -> sin rows 0, cos rows 1 via sincos(0)
        } else {
          const int s = s_items[gi - 1];
          wj = s_wt[s];
          const float t = 2.0f + (4.0f / 127.0f) * (float)s;
          gx = ((ox + dx * t) * (2.0f / 3.0f) + 1.0f) * 63.5f;
          gy = ((oy + dy * t) * (2.0f / 3.0f) + 1.0f) * 63.5f;
          gz = ((oz + dz * t) * (2.0f / 3.0f) + 1.0f) * 63.5f;
          vld = 1;
        }
      }
      s_jw[j] = wj; s_gx[j] = gx; s_gy[j] = gy; s_gz[j] = gz; s_vld[j] = vld;
    }
    __syncthreads();

    // feats rows (27 x 16)
    for (int a2 = tid; a2 < APPC * TILE; a2 += 256) {
      const int j = a2 & (TILE - 1), c = a2 >> 4;
      s_inT[c][j] = s_vld[j]
                        ? tri_sample(agrid + (size_t)c * G * G * G, s_gx[j], s_gy[j], s_gz[j])
                        : 0.0f;
    }
    __syncthreads();

    // PE(feats): sin -> rows 27.., cos -> rows 189..
    for (int a2 = tid; a2 < 162 * TILE; a2 += 256) {
      const int j = a2 & (TILE - 1), idx = a2 >> 4;
      const int d = idx / 6, f = idx % 6;
      float sn, cs; __sincosf(s_inT[d][j] * (float)(1 << f), &sn, &cs);
      s_inT[27 + idx][j]  = sn;
      s_inT[189 + idx][j] = cs;
    }
    __syncthreads();

    const int nrn = tid & 127;
    const int j0  = (tid >> 7) * 8;

    // layer 1 over 351 compact rows, init = hbase
    float a1[8];
    {
      const float hb = s_hbase[nrn];
#pragma unroll
      for (int i = 0; i < 8; ++i) a1[i] = hb;
    }
#pragma unroll 4
    for (int r = 0; r < R1; ++r) {
      const int k = (r < 27) ? r : r + 3;
      const float wv = W1[k * FC + nrn];
      const float4 v0 = *(const float4*)&s_inT[r][j0];
      const float4 v1 = *(const float4*)&s_inT[r][j0 + 4];
      a1[0] = fmaf(v0.x, wv, a1[0]); a1[1] = fmaf(v0.y, wv, a1[1]);
      a1[2] = fmaf(v0.z, wv, a1[2]); a1[3] = fmaf(v0.w, wv, a1[3]);
      a1[4] = fmaf(v1.x, wv, a1[4]); a1[5] = fmaf(v1.y, wv, a1[5]);
      a1[6] = fmaf(v1.z, wv, a1[6]); a1[7] = fmaf(v1.w, wv, a1[7]);
    }
#pragma unroll
    for (int i = 0; i < 8; ++i) s_hT[nrn][j0 + i] = fmaxf(a1[i], 0.0f);
    __syncthreads();

    // layer 2
    float a2v[8];
    {
      const float bb = b2[nrn];
#pragma unroll
      for (int i = 0; i < 8; ++i) a2v[i] = bb;
    }
#pragma unroll 4
    for (int k = 0; k < FC; ++k) {
      const float wv = W2[k * FC + nrn];
      const float4 u0 = *(const float4*)&s_hT[k][j0];
      const float4 u1 = *(const float4*)&s_hT[k][j0 + 4];
      a2v[0] = fmaf(u0.x, wv, a2v[0]); a2v[1] = fmaf(u0.y, wv, a2v[1]);
      a2v[2] = fmaf(u0.z, wv, a2v[2]); a2v[3] = fmaf(u0.w, wv, a2v[3]);
      a2v[4] = fmaf(u1.x, wv, a2v[4]); a2v[5] = fmaf(u1.y, wv, a2v[5]);
      a2v[6] = fmaf(u1.z, wv, a2v[6]); a2v[7] = fmaf(u1.w, wv, a2v[7]);
    }
    float* s_h2 = &s_inT[0][0];  // reuse as [128][20]; layer-1 s_inT reads completed pre-barrier
#pragma unroll
    for (int i = 0; i < 8; ++i) s_h2[nrn * 20 + j0 + i] = fmaxf(a2v[i], 0.0f);
    __syncthreads();

    // layer 3 + per-item rgb*w
    if (tid < 3 * TILE) {
      const int j = tid / 3, c = tid - j * 3;
      if (j < nt) {
        float a3 = b3[c];
#pragma unroll 8
        for (int k = 0; k < FC; ++k)
          a3 = fmaf(s_h2[k * 20 + j], W3[k * 3 + c], a3);
        const float rgb = 1.0f / (1.0f + __expf(-a3));
        s_rgbw[j][c] = s_jw[j] * rgb;
      }
    }
    __syncthreads();
    if (tid < 3) {
      float v = s_out[tid];
      for (int j = 0; j < nt; ++j) v += s_rgbw[j][tid];
      s_out[tid] = v;
    }
    __syncthreads();
  }

  if (tid < 3) {
    const float val = s_out[tid] + (1.0f - acc);
    out[ray * 3 + tid] = fminf(fmaxf(val, 0.0f), 1.0f);
  }
}

extern "C" void kernel_launch(void* const* d_in, const int* in_sizes, int n_in,
                              void* d_out, int out_size, void* d_ws, size_t ws_size,
                              hipStream_t stream) {
  const float* rays_o = (const float*)d_in[0];
  const float* rays_d = (const float*)d_in[1];
  const float* dgrid  = (const float*)d_in[2];
  const float* agrid  = (const float*)d_in[3];
  const float* W1     = (const float*)d_in[4];
  const float* b1     = (const float*)d_in[5];
  const float* W2     = (const float*)d_in[6];
  const float* b2     = (const float*)d_in[7];
  const float* W3     = (const float*)d_in[8];
  const float* b3     = (const float*)d_in[9];
  float* out = (float*)d_out;

  hipLaunchKernelGGL(k_all, dim3(NRAYS), dim3(256), 0, stream,
                     rays_o, rays_d, dgrid, agrid, W1, W2, W3, b1, b2, b3, out);
}

// Round 5
// 80.425 us; speedup vs baseline: 1.3516x; 1.3516x over previous
//
#include <hip/hip_runtime.h>

#define NRAYS 2048
#define NS    128
#define G     128
#define FC    128
#define APPC  27
#define TILE  16
#define R1    351   // compact item rows: 27 feats + 162 sin + 162 cos; W1 row k = r<27 ? r : r+3

static __device__ __forceinline__ float tri_sample(const float* __restrict__ vol,
                                                   float gx, float gy, float gz) {
  int x0 = (int)gx; x0 = x0 < 0 ? 0 : (x0 > G - 2 ? G - 2 : x0);
  int y0 = (int)gy; y0 = y0 < 0 ? 0 : (y0 > G - 2 ? G - 2 : y0);
  int z0 = (int)gz; z0 = z0 < 0 ? 0 : (z0 > G - 2 ? G - 2 : z0);
  float fx = gx - (float)x0;
  float fy = gy - (float)y0;
  float fz = gz - (float)z0;
  const float* p = vol + ((z0 * G + y0) * G + x0);
  float v000 = p[0], v001 = p[1];
  float v010 = p[G], v011 = p[G + 1];
  const float* q = p + G * G;
  float v100 = q[0], v101 = q[1];
  float v110 = q[G], v111 = q[G + 1];
  float c00 = v000 + (v001 - v000) * fx;
  float c01 = v010 + (v011 - v010) * fx;
  float c10 = v100 + (v101 - v100) * fx;
  float c11 = v110 + (v111 - v110) * fx;
  float c0  = c00 + (c01 - c00) * fy;
  float c1  = c10 + (c11 - c10) * fy;
  return c0 + (c1 - c0) * fz;
}

static __device__ __forceinline__ void sample_alpha(const float* __restrict__ dgrid,
                                                    float ox, float oy, float oz,
                                                    float dx, float dy, float dz,
                                                    int s, float& alpha, bool& inb) {
  const float t  = 2.0f + (4.0f / 127.0f) * (float)s;
  const float px = (ox + dx * t) * (2.0f / 3.0f);
  const float py = (oy + dy * t) * (2.0f / 3.0f);
  const float pz = (oz + dz * t) * (2.0f / 3.0f);
  inb = (fabsf(px) <= 1.0f) && (fabsf(py) <= 1.0f) && (fabsf(pz) <= 1.0f);
  float sf = 0.0f;
  if (inb)
    sf = tri_sample(dgrid, (px + 1.0f) * 63.5f, (py + 1.0f) * 63.5f, (pz + 1.0f) * 63.5f);
  const float sigma = log1pf(__expf(sf - 10.0f));
  alpha = 1.0f - __expf(-sigma * 0.78125f);
}

// ---------------- A: wave-per-ray prep (alphas, scan, weights, compaction) ----------------
__global__ __launch_bounds__(256) void k_prep(const float* __restrict__ rays_o,
                                              const float* __restrict__ rays_d,
                                              const float* __restrict__ dgrid,
                                              float* __restrict__ g_dir,
                                              float* __restrict__ g_acc,
                                              float* __restrict__ g_woob,
                                              int* __restrict__ g_icnt,
                                              int* __restrict__ g_iidx,
                                              float* __restrict__ g_iw) {
  const int ray  = blockIdx.x * 4 + (threadIdx.x >> 6);
  const int lane = threadIdx.x & 63;

  const float rdx = rays_d[ray * 3 + 0], rdy = rays_d[ray * 3 + 1], rdz = rays_d[ray * 3 + 2];
  const float inv = rsqrtf(rdx * rdx + rdy * rdy + rdz * rdz);
  const float dx = rdx * inv, dy = rdy * inv, dz = rdz * inv;
  const float ox = rays_o[ray * 3 + 0], oy = rays_o[ray * 3 + 1], oz = rays_o[ray * 3 + 2];
  if (lane == 0) {
    g_dir[ray * 3 + 0] = dx; g_dir[ray * 3 + 1] = dy; g_dir[ray * 3 + 2] = dz;
  }

  const int s0 = lane * 2, s1 = s0 + 1;
  float al0, al1; bool in0, in1;
  sample_alpha(dgrid, ox, oy, oz, dx, dy, dz, s0, al0, in0);
  sample_alpha(dgrid, ox, oy, oz, dx, dy, dz, s1, al1, in1);

  const float p0 = 1.0f - al0 + 1e-10f;
  const float p1 = 1.0f - al1 + 1e-10f;
  float incl = p0 * p1;
#pragma unroll
  for (int off = 1; off < 64; off <<= 1) {
    float v = __shfl_up(incl, off);
    if (lane >= off) incl *= v;
  }
  float excl = __shfl_up(incl, 1);
  if (lane == 0) excl = 1.0f;
  const float w0 = al0 * excl;
  const float w1 = al1 * excl * p0;

  float acc  = w0 + w1;
  float woob = (in0 ? 0.0f : w0) + (in1 ? 0.0f : w1);
#pragma unroll
  for (int off = 32; off > 0; off >>= 1) {
    acc  += __shfl_xor(acc, off);
    woob += __shfl_xor(woob, off);
  }

  const unsigned long long m0 = __ballot(in0);
  const unsigned long long m1 = __ballot(in1);
  const int n_in = (int)__popcll(m0) + (int)__popcll(m1);

  int base = 0;
  if (lane == 0) {
    g_acc[ray]  = acc;
    g_woob[ray] = woob;
    if (n_in) base = atomicAdd(g_icnt, n_in);
  }
  base = __shfl(base, 0);

  const unsigned long long low = (1ull << lane) - 1ull;
  const int r0 = (int)__popcll(m0 & low) + (int)__popcll(m1 & low);
  if (in0) { g_iidx[base + r0] = (ray << 7) | s0; g_iw[base + r0] = w0; }
  if (in1) {
    const int r1 = r0 + (in0 ? 1 : 0);
    g_iidx[base + r1] = (ray << 7) | s1; g_iw[base + r1] = w1;
  }
}

// ---------------- B: per-ray hbase + OOB base color (16 rays / block) ----------------
__global__ __launch_bounds__(256) void k_base(const float* __restrict__ g_dir,
                                              const float* __restrict__ g_acc,
                                              const float* __restrict__ g_woob,
                                              const float* __restrict__ W1,
                                              const float* __restrict__ W2,
                                              const float* __restrict__ W3,
                                              const float* __restrict__ b1,
                                              const float* __restrict__ b2,
                                              const float* __restrict__ b3,
                                              float* __restrict__ g_hbase,
                                              float* __restrict__ out) {
  const int r0  = blockIdx.x * 16;
  const int tid = threadIdx.x;
  __shared__ float s_in[39][TILE];   // rows 0-2: vd; 3-20: sin(vd); 21-38: cos(vd)
  __shared__ float s_h1[FC][20];
  __shared__ float s_h2[FC][20];
  __shared__ float s_bc[FC], s_ps[FC];

  if (tid < 48) {
    const int d = tid >> 4, j = tid & 15;
    s_in[d][j] = g_dir[(r0 + j) * 3 + d];
  }
  __syncthreads();
  for (int a = tid; a < 18 * TILE; a += 256) {
    const int j = a & 15, idx = a >> 4, d = idx / 6, f = idx % 6;
    float sn, cs; __sincosf(s_in[d][j] * (float)(1 << f), &sn, &cs);
    s_in[3 + idx][j]  = sn;
    s_in[21 + idx][j] = cs;
  }
  {  // cos(0)-block column sums, two interleaved halves
    const int nrn = tid & 127, h = tid >> 7;
    float v = 0.0f;
#pragma unroll 9
    for (int k = 192 + h; k < 354; k += 2) v += W1[k * FC + nrn];
    if (h) s_ps[nrn] = v; else s_bc[nrn] = v;
  }
  __syncthreads();

  const int nrn = tid & 127;
  const int j0  = (tid >> 7) * 8;

  float a1[8];
  {
    const float bb = b1[nrn];
#pragma unroll
    for (int i = 0; i < 8; ++i) a1[i] = bb;
  }
#pragma unroll
  for (int r = 0; r < 39; ++r) {
    const int k = (r < 3) ? (27 + r) : (351 + r);
    const float wv = W1[k * FC + nrn];
    const float4 v0 = *(const float4*)&s_in[r][j0];
    const float4 v1 = *(const float4*)&s_in[r][j0 + 4];
    a1[0] = fmaf(v0.x, wv, a1[0]); a1[1] = fmaf(v0.y, wv, a1[1]);
    a1[2] = fmaf(v0.z, wv, a1[2]); a1[3] = fmaf(v0.w, wv, a1[3]);
    a1[4] = fmaf(v1.x, wv, a1[4]); a1[5] = fmaf(v1.y, wv, a1[5]);
    a1[6] = fmaf(v1.z, wv, a1[6]); a1[7] = fmaf(v1.w, wv, a1[7]);
  }
  const float bcv = s_bc[nrn] + s_ps[nrn];
#pragma unroll
  for (int i = 0; i < 8; ++i) {
    g_hbase[(size_t)(r0 + j0 + i) * FC + nrn] = a1[i];
    s_h1[nrn][j0 + i] = fmaxf(a1[i] + bcv, 0.0f);
  }
  __syncthreads();

  float a2[8];
  {
    const float bb = b2[nrn];
#pragma unroll
    for (int i = 0; i < 8; ++i) a2[i] = bb;
  }
#pragma unroll 4
  for (int k = 0; k < FC; ++k) {
    const float wv = W2[k * FC + nrn];
    const float4 u0 = *(const float4*)&s_h1[k][j0];
    const float4 u1 = *(const float4*)&s_h1[k][j0 + 4];
    a2[0] = fmaf(u0.x, wv, a2[0]); a2[1] = fmaf(u0.y, wv, a2[1]);
    a2[2] = fmaf(u0.z, wv, a2[2]); a2[3] = fmaf(u0.w, wv, a2[3]);
    a2[4] = fmaf(u1.x, wv, a2[4]); a2[5] = fmaf(u1.y, wv, a2[5]);
    a2[6] = fmaf(u1.z, wv, a2[6]); a2[7] = fmaf(u1.w, wv, a2[7]);
  }
#pragma unroll
  for (int i = 0; i < 8; ++i) s_h2[nrn][j0 + i] = fmaxf(a2[i], 0.0f);
  __syncthreads();

  if (tid < 48) {
    const int j = tid / 3, c = tid - j * 3;
    float a3 = b3[c];
#pragma unroll 8
    for (int k = 0; k < FC; ++k)
      a3 = fmaf(s_h2[k][j], W3[k * 3 + c], a3);
    const float rgb = 1.0f / (1.0f + __expf(-a3));
    const int ray = r0 + j;
    out[ray * 3 + c] = g_woob[ray] * rgb + (1.0f - g_acc[ray]);
  }
}

// ---------------- C: batched item MLP over globally compacted list ----------------
__global__ __launch_bounds__(256) void k_items(const float* __restrict__ rays_o,
                                               const float* __restrict__ g_dir,
                                               const float* __restrict__ agrid,
                                               const float* __restrict__ W1,
                                               const float* __restrict__ W2,
                                               const float* __restrict__ W3,
                                               const float* __restrict__ b2,
                                               const float* __restrict__ b3,
                                               const float* __restrict__ g_hbase,
                                               const int* __restrict__ g_iidx,
                                               const float* __restrict__ g_iw,
                                               const int* __restrict__ g_icnt,
                                               float* __restrict__ out) {
  const int tid = threadIdx.x;
  __shared__ float s_inT[R1][TILE];   // 22.5 KB; tail-reused as h2 [128][20]
  __shared__ float s_hT[FC][20];      // 10 KB
  __shared__ int   s_rayid[TILE];
  __shared__ float s_jw[TILE], s_gx[TILE], s_gy[TILE], s_gz[TILE];
  __shared__ int   s_vld[TILE];

  const int n      = *g_icnt;
  const int ntiles = (n + TILE - 1) >> 4;

  for (int tile = blockIdx.x; tile < ntiles; tile += gridDim.x) {
    if (tid < TILE) {
      const int gi  = tile * TILE + tid;
      const int vld = gi < n;
      const int idx = vld ? g_iidx[gi] : 0;
      const int ray = idx >> 7, s = idx & (NS - 1);
      s_rayid[tid] = ray;
      s_vld[tid]   = vld;
      s_jw[tid]    = vld ? g_iw[gi] : 0.0f;
      const float dxx = g_dir[ray * 3 + 0], dyy = g_dir[ray * 3 + 1], dzz = g_dir[ray * 3 + 2];
      const float t = 2.0f + (4.0f / 127.0f) * (float)s;
      s_gx[tid] = ((rays_o[ray * 3 + 0] + dxx * t) * (2.0f / 3.0f) + 1.0f) * 63.5f;
      s_gy[tid] = ((rays_o[ray * 3 + 1] + dyy * t) * (2.0f / 3.0f) + 1.0f) * 63.5f;
      s_gz[tid] = ((rays_o[ray * 3 + 2] + dzz * t) * (2.0f / 3.0f) + 1.0f) * 63.5f;
    }
    __syncthreads();

    for (int a = tid; a < APPC * TILE; a += 256) {
      const int j = a & (TILE - 1), c = a >> 4;
      s_inT[c][j] = s_vld[j]
                        ? tri_sample(agrid + (size_t)c * G * G * G, s_gx[j], s_gy[j], s_gz[j])
                        : 0.0f;
    }
    __syncthreads();

    for (int a = tid; a < 162 * TILE; a += 256) {
      const int j = a & (TILE - 1), idx = a >> 4;
      const int d = idx / 6, f = idx % 6;
      float sn, cs; __sincosf(s_inT[d][j] * (float)(1 << f), &sn, &cs);
      s_inT[27 + idx][j]  = sn;
      s_inT[189 + idx][j] = cs;
    }
    __syncthreads();

    const int nrn = tid & 127;
    const int j0  = (tid >> 7) * 8;

    float a1[8];
#pragma unroll
    for (int i = 0; i < 8; ++i)
      a1[i] = g_hbase[(size_t)s_rayid[j0 + i] * FC + nrn];

    const float* w1p = W1 + nrn;
#pragma unroll 9
    for (int r = 0; r < 27; ++r) {
      const float wv = w1p[r * FC];
      const float4 v0 = *(const float4*)&s_inT[r][j0];
      const float4 v1 = *(const float4*)&s_inT[r][j0 + 4];
      a1[0] = fmaf(v0.x, wv, a1[0]); a1[1] = fmaf(v0.y, wv, a1[1]);
      a1[2] = fmaf(v0.z, wv, a1[2]); a1[3] = fmaf(v0.w, wv, a1[3]);
      a1[4] = fmaf(v1.x, wv, a1[4]); a1[5] = fmaf(v1.y, wv, a1[5]);
      a1[6] = fmaf(v1.z, wv, a1[6]); a1[7] = fmaf(v1.w, wv, a1[7]);
    }
#pragma unroll 8
    for (int r = 27; r < R1; ++r) {
      const float wv = w1p[(r + 3) * FC];
      const float4 v0 = *(const float4*)&s_inT[r][j0];
      const float4 v1 = *(const float4*)&s_inT[r][j0 + 4];
      a1[0] = fmaf(v0.x, wv, a1[0]); a1[1] = fmaf(v0.y, wv, a1[1]);
      a1[2] = fmaf(v0.z, wv, a1[2]); a1[3] = fmaf(v0.w, wv, a1[3]);
      a1[4] = fmaf(v1.x, wv, a1[4]); a1[5] = fmaf(v1.y, wv, a1[5]);
      a1[6] = fmaf(v1.z, wv, a1[6]); a1[7] = fmaf(v1.w, wv, a1[7]);
    }
#pragma unroll
    for (int i = 0; i < 8; ++i) s_hT[nrn][j0 + i] = fmaxf(a1[i], 0.0f);
    __syncthreads();

    float a2[8];
    {
      const float bb = b2[nrn];
#pragma unroll
      for (int i = 0; i < 8; ++i) a2[i] = bb;
    }
#pragma unroll 4
    for (int k = 0; k < FC; ++k) {
      const float wv = W2[k * FC + nrn];
      const float4 u0 = *(const float4*)&s_hT[k][j0];
      const float4 u1 = *(const float4*)&s_hT[k][j0 + 4];
      a2[0] = fmaf(u0.x, wv, a2[0]); a2[1] = fmaf(u0.y, wv, a2[1]);
      a2[2] = fmaf(u0.z, wv, a2[2]); a2[3] = fmaf(u0.w, wv, a2[3]);
      a2[4] = fmaf(u1.x, wv, a2[4]); a2[5] = fmaf(u1.y, wv, a2[5]);
      a2[6] = fmaf(u1.z, wv, a2[6]); a2[7] = fmaf(u1.w, wv, a2[7]);
    }
    float* s_h2 = &s_inT[0][0];  // reuse as [128][20]; all s_inT reads finished pre-barrier
#pragma unroll
    for (int i = 0; i < 8; ++i) s_h2[nrn * 20 + j0 + i] = fmaxf(a2[i], 0.0f);
    __syncthreads();

    if (tid < 3 * TILE) {
      const int j = tid / 3, c = tid - j * 3;
      if (s_vld[j] && s_jw[j] != 0.0f) {
        float a3 = b3[c];
#pragma unroll 8
        for (int k = 0; k < FC; ++k)
          a3 = fmaf(s_h2[k * 20 + j], W3[k * 3 + c], a3);
        const float rgb = 1.0f / (1.0f + __expf(-a3));
        atomicAdd(&out[s_rayid[j] * 3 + c], s_jw[j] * rgb);
      }
    }
    __syncthreads();
  }
}

extern "C" void kernel_launch(void* const* d_in, const int* in_sizes, int n_in,
                              void* d_out, int out_size, void* d_ws, size_t ws_size,
                              hipStream_t stream) {
  const float* rays_o = (const float*)d_in[0];
  const float* rays_d = (const float*)d_in[1];
  const float* dgrid  = (const float*)d_in[2];
  const float* agrid  = (const float*)d_in[3];
  const float* W1     = (const float*)d_in[4];
  const float* b1     = (const float*)d_in[5];
  const float* W2     = (const float*)d_in[6];
  const float* b2     = (const float*)d_in[7];
  const float* W3     = (const float*)d_in[8];
  const float* b3     = (const float*)d_in[9];
  float* out = (float*)d_out;

  // ws layout (bytes)
  char* ws = (char*)d_ws;
  int*   g_icnt  = (int*)(ws);                       // 4
  float* g_dir   = (float*)(ws + 256);               // 24576
  float* g_acc   = (float*)(ws + 24832);             // 8192
  float* g_woob  = (float*)(ws + 33024);             // 8192
  float* g_hbase = (float*)(ws + 41216);             // 1 MB (2048*128*4)
  int*   g_iidx  = (int*)(ws + 41216 + 1048576);     // 1 MB (262144 cap)
  float* g_iw    = (float*)(ws + 41216 + 2097152);   // 1 MB

  hipMemsetAsync(g_icnt, 0, sizeof(int), stream);
  hipLaunchKernelGGL(k_prep, dim3(NRAYS / 4), dim3(256), 0, stream,
                     rays_o, rays_d, dgrid, g_dir, g_acc, g_woob, g_icnt, g_iidx, g_iw);
  hipLaunchKernelGGL(k_base, dim3(NRAYS / 16), dim3(256), 0, stream,
                     g_dir, g_acc, g_woob, W1, W2, W3, b1, b2, b3, g_hbase, out);
  hipLaunchKernelGGL(k_items, dim3(1024), dim3(256), 0, stream,
                     rays_o, g_dir, agrid, W1, W2, W3, b2, b3,
                     g_hbase, g_iidx, g_iw, g_icnt, out);
}

// Round 7
// 77.167 us; speedup vs baseline: 1.4087x; 1.0422x over previous
//
#include <hip/hip_runtime.h>

#define NRAYS 2048
#define NS    128
#define G     128
#define FC    128
#define APPC  27
#define TILE  16
#define R1    351   // compact item rows: 27 feats + 162 sin + 162 cos; W1 row k = r<27 ? r : r+3

static __device__ __forceinline__ float tri_sample(const float* __restrict__ vol,
                                                   float gx, float gy, float gz) {
  int x0 = (int)gx; x0 = x0 < 0 ? 0 : (x0 > G - 2 ? G - 2 : x0);
  int y0 = (int)gy; y0 = y0 < 0 ? 0 : (y0 > G - 2 ? G - 2 : y0);
  int z0 = (int)gz; z0 = z0 < 0 ? 0 : (z0 > G - 2 ? G - 2 : z0);
  float fx = gx - (float)x0;
  float fy = gy - (float)y0;
  float fz = gz - (float)z0;
  const float* p = vol + ((z0 * G + y0) * G + x0);
  float v000 = p[0], v001 = p[1];
  float v010 = p[G], v011 = p[G + 1];
  const float* q = p + G * G;
  float v100 = q[0], v101 = q[1];
  float v110 = q[G], v111 = q[G + 1];
  float c00 = v000 + (v001 - v000) * fx;
  float c01 = v010 + (v011 - v010) * fx;
  float c10 = v100 + (v101 - v100) * fx;
  float c11 = v110 + (v111 - v110) * fx;
  float c0  = c00 + (c01 - c00) * fy;
  float c1  = c10 + (c11 - c10) * fy;
  return c0 + (c1 - c0) * fz;
}

// softplus(x) for x <= ~-5: log1p(e^x) = e^x - e^x^2/2 + O(e^3x); abs error < 1e-8
static __device__ __forceinline__ float sample_alpha(const float* __restrict__ dgrid,
                                                     float ox, float oy, float oz,
                                                     float dx, float dy, float dz,
                                                     int s, bool& inb) {
  const float t  = 2.0f + (4.0f / 127.0f) * (float)s;
  const float px = (ox + dx * t) * (2.0f / 3.0f);
  const float py = (oy + dy * t) * (2.0f / 3.0f);
  const float pz = (oz + dz * t) * (2.0f / 3.0f);
  inb = (fabsf(px) <= 1.0f) && (fabsf(py) <= 1.0f) && (fabsf(pz) <= 1.0f);
  float sf = 0.0f;
  if (inb)
    sf = tri_sample(dgrid, (px + 1.0f) * 63.5f, (py + 1.0f) * 63.5f, (pz + 1.0f) * 63.5f);
  const float y  = __expf(sf - 10.0f);          // <= ~7e-3 always
  const float sp = y - 0.5f * y * y;            // softplus(sf-10) to ~1e-9
  return 1.0f - __expf(-sp * 0.78125f);
}

// ---------------- K1: prep (blocks 0-511) || base (blocks 512-639) ----------------
__global__ __launch_bounds__(256) void k_phase1(
    const float* __restrict__ rays_o, const float* __restrict__ rays_d,
    const float* __restrict__ dgrid,
    const float* __restrict__ W1, const float* __restrict__ W2,
    const float* __restrict__ W3, const float* __restrict__ b1,
    const float* __restrict__ b2, const float* __restrict__ b3,
    float* __restrict__ out, float* __restrict__ g_dir,
    float* __restrict__ g_woob, float* __restrict__ g_hbase,
    float* __restrict__ g_rgboob, int* __restrict__ g_icnt,
    int* __restrict__ g_iidx, float* __restrict__ g_iw) {
  const int bid = blockIdx.x;
  const int tid = threadIdx.x;

  if (bid < 512) {
    // ---- prep: one wave per ray ----
    const int ray  = bid * 4 + (tid >> 6);
    const int lane = tid & 63;

    const float rdx = rays_d[ray * 3 + 0], rdy = rays_d[ray * 3 + 1], rdz = rays_d[ray * 3 + 2];
    const float inv = rsqrtf(rdx * rdx + rdy * rdy + rdz * rdz);
    const float dx = rdx * inv, dy = rdy * inv, dz = rdz * inv;
    const float ox = rays_o[ray * 3 + 0], oy = rays_o[ray * 3 + 1], oz = rays_o[ray * 3 + 2];
    if (lane == 0) {
      g_dir[ray * 3 + 0] = dx; g_dir[ray * 3 + 1] = dy; g_dir[ray * 3 + 2] = dz;
    }

    const int s0 = lane * 2, s1 = s0 + 1;
    bool in0, in1;
    const float al0 = sample_alpha(dgrid, ox, oy, oz, dx, dy, dz, s0, in0);
    const float al1 = sample_alpha(dgrid, ox, oy, oz, dx, dy, dz, s1, in1);

    const float p0 = 1.0f - al0 + 1e-10f;
    const float p1 = 1.0f - al1 + 1e-10f;
    float incl = p0 * p1;
#pragma unroll
    for (int off = 1; off < 64; off <<= 1) {
      float v = __shfl_up(incl, off);
      if (lane >= off) incl *= v;
    }
    float excl = __shfl_up(incl, 1);
    if (lane == 0) excl = 1.0f;
    const float w0 = al0 * excl;
    const float w1 = al1 * excl * p0;

    float acc  = w0 + w1;
    float woob = (in0 ? 0.0f : w0) + (in1 ? 0.0f : w1);
#pragma unroll
    for (int off = 32; off > 0; off >>= 1) {
      acc  += __shfl_xor(acc, off);
      woob += __shfl_xor(woob, off);
    }

    const unsigned long long m0 = __ballot(in0);
    const unsigned long long m1 = __ballot(in1);
    const int n_in = (int)__popcll(m0) + (int)__popcll(m1);

    int base = 0;
    if (lane == 0) {
      g_woob[ray] = woob;
      if (n_in) base = atomicAdd(g_icnt, n_in);
    }
    base = __shfl(base, 0);
    if (lane < 3) out[ray * 3 + lane] = 1.0f - acc;   // K2 atomically adds onto this

    const unsigned long long low = (1ull << lane) - 1ull;
    const int r0 = (int)__popcll(m0 & low) + (int)__popcll(m1 & low);
    if (in0) { g_iidx[base + r0] = (ray << 7) | s0; g_iw[base + r0] = w0; }
    if (in1) {
      const int r1 = r0 + (in0 ? 1 : 0);
      g_iidx[base + r1] = (ray << 7) | s1; g_iw[base + r1] = w1;
    }
    return;
  }

  // ---- base: 16 rays per block -> g_hbase + g_rgboob (independent of prep) ----
  __shared__ float s_in[39][TILE];   // rows 0-2 vd; 3-20 sin(vd); 21-38 cos(vd)
  __shared__ float s_h1[FC][20];
  __shared__ float s_h2[FC][20];
  __shared__ float s_bc[FC], s_ps[FC];

  const int r0 = (bid - 512) * 16;
  if (tid < 16) {
    const int j = tid;
    const float rdx = rays_d[(r0 + j) * 3 + 0], rdy = rays_d[(r0 + j) * 3 + 1],
                rdz = rays_d[(r0 + j) * 3 + 2];
    const float inv = rsqrtf(rdx * rdx + rdy * rdy + rdz * rdz);
    s_in[0][j] = rdx * inv;
    s_in[1][j] = rdy * inv;
    s_in[2][j] = rdz * inv;
  }
  {  // cos(0)-block column sums, two interleaved halves (no dep on s_in)
    const int nrn = tid & 127, h = tid >> 7;
    float v = 0.0f;
#pragma unroll 9
    for (int k = 192 + h; k < 354; k += 2) v += W1[k * FC + nrn];
    if (h) s_ps[nrn] = v; else s_bc[nrn] = v;
  }
  __syncthreads();
  for (int a = tid; a < 18 * TILE; a += 256) {
    const int j = a & 15, idx = a >> 4, d = idx / 6, f = idx % 6;
    float sn, cs; __sincosf(s_in[d][j] * (float)(1 << f), &sn, &cs);
    s_in[3 + idx][j]  = sn;
    s_in[21 + idx][j] = cs;
  }
  __syncthreads();

  const int nrn = tid & 127;
  const int j0  = (tid >> 7) * 8;

  float a1[8];
  {
    const float bb = b1[nrn];
#pragma unroll
    for (int i = 0; i < 8; ++i) a1[i] = bb;
  }
#pragma unroll
  for (int r = 0; r < 39; ++r) {
    const int k = (r < 3) ? (27 + r) : (351 + r);
    const float wv = W1[k * FC + nrn];
    const float4 v0 = *(const float4*)&s_in[r][j0];
    const float4 v1 = *(const float4*)&s_in[r][j0 + 4];
    a1[0] = fmaf(v0.x, wv, a1[0]); a1[1] = fmaf(v0.y, wv, a1[1]);
    a1[2] = fmaf(v0.z, wv, a1[2]); a1[3] = fmaf(v0.w, wv, a1[3]);
    a1[4] = fmaf(v1.x, wv, a1[4]); a1[5] = fmaf(v1.y, wv, a1[5]);
    a1[6] = fmaf(v1.z, wv, a1[6]); a1[7] = fmaf(v1.w, wv, a1[7]);
  }
  const float bcv = s_bc[nrn] + s_ps[nrn];
#pragma unroll
  for (int i = 0; i < 8; ++i) {
    g_hbase[(size_t)(r0 + j0 + i) * FC + nrn] = a1[i];
    s_h1[nrn][j0 + i] = fmaxf(a1[i] + bcv, 0.0f);
  }
  __syncthreads();

  float a2[8];
  {
    const float bb = b2[nrn];
#pragma unroll
    for (int i = 0; i < 8; ++i) a2[i] = bb;
  }
#pragma unroll 4
  for (int k = 0; k < FC; ++k) {
    const float wv = W2[k * FC + nrn];
    const float4 u0 = *(const float4*)&s_h1[k][j0];
    const float4 u1 = *(const float4*)&s_h1[k][j0 + 4];
    a2[0] = fmaf(u0.x, wv, a2[0]); a2[1] = fmaf(u0.y, wv, a2[1]);
    a2[2] = fmaf(u0.z, wv, a2[2]); a2[3] = fmaf(u0.w, wv, a2[3]);
    a2[4] = fmaf(u1.x, wv, a2[4]); a2[5] = fmaf(u1.y, wv, a2[5]);
    a2[6] = fmaf(u1.z, wv, a2[6]); a2[7] = fmaf(u1.w, wv, a2[7]);
  }
#pragma unroll
  for (int i = 0; i < 8; ++i) s_h2[nrn][j0 + i] = fmaxf(a2[i], 0.0f);
  __syncthreads();

  if (tid < 48) {
    const int j = tid / 3, c = tid - j * 3;
    float a3 = b3[c];
#pragma unroll 8
    for (int k = 0; k < FC; ++k)
      a3 = fmaf(s_h2[k][j], W3[k * 3 + c], a3);
    g_rgboob[(r0 + j) * 3 + c] = 1.0f / (1.0f + __expf(-a3));
  }
}

// ---------------- K2: 8 OOB-composite tiles + batched item MLP ----------------
__global__ __launch_bounds__(256) void k_items(const float* __restrict__ rays_o,
                                               const float* __restrict__ g_dir,
                                               const float* __restrict__ agrid,
                                               const float* __restrict__ W1,
                                               const float* __restrict__ W2,
                                               const float* __restrict__ W3,
                                               const float* __restrict__ b2,
                                               const float* __restrict__ b3,
                                               const float* __restrict__ g_hbase,
                                               const float* __restrict__ g_woob,
                                               const float* __restrict__ g_rgboob,
                                               const int* __restrict__ g_iidx,
                                               const float* __restrict__ g_iw,
                                               const int* __restrict__ g_icnt,
                                               float* __restrict__ out) {
  const int tid = threadIdx.x;
  __shared__ float s_inT[R1][TILE];   // 22.5 KB; tail-reused as h2 [128][20]
  __shared__ float s_hT[FC][20];      // 10 KB
  __shared__ int   s_rayid[TILE];
  __shared__ float s_jw[TILE], s_gx[TILE], s_gy[TILE], s_gz[TILE];
  __shared__ int   s_vld[TILE];

  const int n      = *g_icnt;
  const int ntiles = 8 + ((n + TILE - 1) >> 4);

  for (int tile = blockIdx.x; tile < ntiles; tile += gridDim.x) {
    if (tile < 8) {   // OOB composite (block-uniform branch, no barriers inside)
      const int ray = tile * 256 + tid;
      const float wv = g_woob[ray];
#pragma unroll
      for (int c = 0; c < 3; ++c)
        atomicAdd(&out[ray * 3 + c], wv * g_rgboob[ray * 3 + c]);
      continue;
    }
    const int it = tile - 8;

    if (tid < TILE) {
      const int gi  = it * TILE + tid;
      const int vld = gi < n;
      const int idx = vld ? g_iidx[gi] : 0;
      const int ray = idx >> 7, s = idx & (NS - 1);
      s_rayid[tid] = ray;
      s_vld[tid]   = vld;
      s_jw[tid]    = vld ? g_iw[gi] : 0.0f;
      const float dxx = g_dir[ray * 3 + 0], dyy = g_dir[ray * 3 + 1], dzz = g_dir[ray * 3 + 2];
      const float t = 2.0f + (4.0f / 127.0f) * (float)s;
      s_gx[tid] = ((rays_o[ray * 3 + 0] + dxx * t) * (2.0f / 3.0f) + 1.0f) * 63.5f;
      s_gy[tid] = ((rays_o[ray * 3 + 1] + dyy * t) * (2.0f / 3.0f) + 1.0f) * 63.5f;
      s_gz[tid] = ((rays_o[ray * 3 + 2] + dzz * t) * (2.0f / 3.0f) + 1.0f) * 63.5f;
    }
    __syncthreads();

    for (int a = tid; a < APPC * TILE; a += 256) {
      const int j = a & (TILE - 1), c = a >> 4;
      s_inT[c][j] = s_vld[j]
                        ? tri_sample(agrid + (size_t)c * G * G * G, s_gx[j], s_gy[j], s_gz[j])
                        : 0.0f;
    }
    __syncthreads();

    for (int a = tid; a < 162 * TILE; a += 256) {
      const int j = a & (TILE - 1), idx = a >> 4;
      const int d = idx / 6, f = idx % 6;
      float sn, cs; __sincosf(s_inT[d][j] * (float)(1 << f), &sn, &cs);
      s_inT[27 + idx][j]  = sn;
      s_inT[189 + idx][j] = cs;
    }
    __syncthreads();

    const int nrn = tid & 127;
    const int j0  = (tid >> 7) * 8;

    float a1[8];
#pragma unroll
    for (int i = 0; i < 8; ++i)
      a1[i] = g_hbase[(size_t)s_rayid[j0 + i] * FC + nrn];

    const float* w1p = W1 + nrn;
#pragma unroll 9
    for (int r = 0; r < 27; ++r) {
      const float wv = w1p[r * FC];
      const float4 v0 = *(const float4*)&s_inT[r][j0];
      const float4 v1 = *(const float4*)&s_inT[r][j0 + 4];
      a1[0] = fmaf(v0.x, wv, a1[0]); a1[1] = fmaf(v0.y, wv, a1[1]);
      a1[2] = fmaf(v0.z, wv, a1[2]); a1[3] = fmaf(v0.w, wv, a1[3]);
      a1[4] = fmaf(v1.x, wv, a1[4]); a1[5] = fmaf(v1.y, wv, a1[5]);
      a1[6] = fmaf(v1.z, wv, a1[6]); a1[7] = fmaf(v1.w, wv, a1[7]);
    }
#pragma unroll 8
    for (int r = 27; r < R1; ++r) {
      const float wv = w1p[(r + 3) * FC];
      const float4 v0 = *(const float4*)&s_inT[r][j0];
      const float4 v1 = *(const float4*)&s_inT[r][j0 + 4];
      a1[0] = fmaf(v0.x, wv, a1[0]); a1[1] = fmaf(v0.y, wv, a1[1]);
      a1[2] = fmaf(v0.z, wv, a1[2]); a1[3] = fmaf(v0.w, wv, a1[3]);
      a1[4] = fmaf(v1.x, wv, a1[4]); a1[5] = fmaf(v1.y, wv, a1[5]);
      a1[6] = fmaf(v1.z, wv, a1[6]); a1[7] = fmaf(v1.w, wv, a1[7]);
    }
#pragma unroll
    for (int i = 0; i < 8; ++i) s_hT[nrn][j0 + i] = fmaxf(a1[i], 0.0f);
    __syncthreads();

    float a2[8];
    {
      const float bb = b2[nrn];
#pragma unroll
      for (int i = 0; i < 8; ++i) a2[i] = bb;
    }
#pragma unroll 4
    for (int k = 0; k < FC; ++k) {
      const float wv = W2[k * FC + nrn];
      const float4 u0 = *(const float4*)&s_hT[k][j0];
      const float4 u1 = *(const float4*)&s_hT[k][j0 + 4];
      a2[0] = fmaf(u0.x, wv, a2[0]); a2[1] = fmaf(u0.y, wv, a2[1]);
      a2[2] = fmaf(u0.z, wv, a2[2]); a2[3] = fmaf(u0.w, wv, a2[3]);
      a2[4] = fmaf(u1.x, wv, a2[4]); a2[5] = fmaf(u1.y, wv, a2[5]);
      a2[6] = fmaf(u1.z, wv, a2[6]); a2[7] = fmaf(u1.w, wv, a2[7]);
    }
    float* s_h2 = &s_inT[0][0];  // reuse as [128][20]; all s_inT reads finished pre-barrier
#pragma unroll
    for (int i = 0; i < 8; ++i) s_h2[nrn * 20 + j0 + i] = fmaxf(a2[i], 0.0f);
    __syncthreads();

    if (tid < 3 * TILE) {
      const int j = tid / 3, c = tid - j * 3;
      if (s_vld[j] && s_jw[j] != 0.0f) {
        float a3 = b3[c];
#pragma unroll 8
        for (int k = 0; k < FC; ++k)
          a3 = fmaf(s_h2[k * 20 + j], W3[k * 3 + c], a3);
        const float rgb = 1.0f / (1.0f + __expf(-a3));
        atomicAdd(&out[s_rayid[j] * 3 + c], s_jw[j] * rgb);
      }
    }
    __syncthreads();
  }
}

extern "C" void kernel_launch(void* const* d_in, const int* in_sizes, int n_in,
                              void* d_out, int out_size, void* d_ws, size_t ws_size,
                              hipStream_t stream) {
  const float* rays_o = (const float*)d_in[0];
  const float* rays_d = (const float*)d_in[1];
  const float* dgrid  = (const float*)d_in[2];
  const float* agrid  = (const float*)d_in[3];
  const float* W1     = (const float*)d_in[4];
  const float* b1     = (const float*)d_in[5];
  const float* W2     = (const float*)d_in[6];
  const float* b2     = (const float*)d_in[7];
  const float* W3     = (const float*)d_in[8];
  const float* b3     = (const float*)d_in[9];
  float* out = (float*)d_out;

  char* ws = (char*)d_ws;
  int*   g_icnt   = (int*)(ws);                      // 4 B
  float* g_dir    = (float*)(ws + 1024);             // 24 KB
  float* g_woob   = (float*)(ws + 25600);            // 8 KB
  float* g_rgboob = (float*)(ws + 33792);            // 24 KB
  float* g_hbase  = (float*)(ws + 65536);            // 1 MB
  int*   g_iidx   = (int*)(ws + 65536 + 1048576);    // 1 MB (262144 cap)
  float* g_iw     = (float*)(ws + 65536 + 2097152);  // 1 MB

  hipMemsetAsync(g_icnt, 0, sizeof(int), stream);
  hipLaunchKernelGGL(k_phase1, dim3(640), dim3(256), 0, stream,
                     rays_o, rays_d, dgrid, W1, W2, W3, b1, b2, b3,
                     out, g_dir, g_woob, g_hbase, g_rgboob, g_icnt, g_iidx, g_iw);
  hipLaunchKernelGGL(k_items, dim3(1024), dim3(256), 0, stream,
                     rays_o, g_dir, agrid, W1, W2, W3, b2, b3,
                     g_hbase, g_woob, g_rgboob, g_iidx, g_iw, g_icnt, out);
}

// Round 8
// 62.756 us; speedup vs baseline: 1.7322x; 1.2296x over previous
//
#include <hip/hip_runtime.h>

#define NRAYS 2048
#define NS    128
#define G     128
#define FC    128
#define APPC  27
#define TILE  16
#define MAXP  48    // max in-bounds samples per ray (geometric bound ~34)
#define R1    351   // compact item rows: 27 feats + 162 sin + 162 cos; W1 row k = r<27 ? r : r+3

static __device__ __forceinline__ float tri_sample(const float* __restrict__ vol,
                                                   float gx, float gy, float gz) {
  int x0 = (int)gx; x0 = x0 < 0 ? 0 : (x0 > G - 2 ? G - 2 : x0);
  int y0 = (int)gy; y0 = y0 < 0 ? 0 : (y0 > G - 2 ? G - 2 : y0);
  int z0 = (int)gz; z0 = z0 < 0 ? 0 : (z0 > G - 2 ? G - 2 : z0);
  float fx = gx - (float)x0;
  float fy = gy - (float)y0;
  float fz = gz - (float)z0;
  const float* p = vol + ((z0 * G + y0) * G + x0);
  float v000 = p[0], v001 = p[1];
  float v010 = p[G], v011 = p[G + 1];
  const float* q = p + G * G;
  float v100 = q[0], v101 = q[1];
  float v110 = q[G], v111 = q[G + 1];
  float c00 = v000 + (v001 - v000) * fx;
  float c01 = v010 + (v011 - v010) * fx;
  float c10 = v100 + (v101 - v100) * fx;
  float c11 = v110 + (v111 - v110) * fx;
  float c0  = c00 + (c01 - c00) * fy;
  float c1  = c10 + (c11 - c10) * fy;
  return c0 + (c1 - c0) * fz;
}

// softplus(x) for x <= ~-5: log1p(e^x) = e^x - e^x^2/2 + O(e^3x); abs error < 1e-8
static __device__ __forceinline__ float sample_alpha(const float* __restrict__ dgrid,
                                                     float ox, float oy, float oz,
                                                     float dx, float dy, float dz,
                                                     int s, bool& inb) {
  const float t  = 2.0f + (4.0f / 127.0f) * (float)s;
  const float px = (ox + dx * t) * (2.0f / 3.0f);
  const float py = (oy + dy * t) * (2.0f / 3.0f);
  const float pz = (oz + dz * t) * (2.0f / 3.0f);
  inb = (fabsf(px) <= 1.0f) && (fabsf(py) <= 1.0f) && (fabsf(pz) <= 1.0f);
  float sf = 0.0f;
  if (inb)
    sf = tri_sample(dgrid, (px + 1.0f) * 63.5f, (py + 1.0f) * 63.5f, (pz + 1.0f) * 63.5f);
  const float y  = __expf(sf - 10.0f);          // <= ~7e-3 always
  const float sp = y - 0.5f * y * y;            // softplus(sf-10) to ~1e-9
  return 1.0f - __expf(-sp * 0.78125f);
}

// ---------------- K1: prep (blocks 0-511, wave/ray) || base (blocks 512-639) ----------------
__global__ __launch_bounds__(256) void k_phase1(
    const float* __restrict__ rays_o, const float* __restrict__ rays_d,
    const float* __restrict__ dgrid,
    const float* __restrict__ W1, const float* __restrict__ W2,
    const float* __restrict__ W3, const float* __restrict__ b1,
    const float* __restrict__ b2, const float* __restrict__ b3,
    float* __restrict__ out, float* __restrict__ g_dir,
    float* __restrict__ g_woob, float* __restrict__ g_hbase,
    float* __restrict__ g_rgboob, int* __restrict__ g_cnt,
    unsigned char* __restrict__ g_sidx, float* __restrict__ g_w) {
  const int bid = blockIdx.x;
  const int tid = threadIdx.x;

  if (bid < 512) {
    // ---- prep: one wave per ray; no global atomics, per-ray fixed slots ----
    const int ray  = bid * 4 + (tid >> 6);
    const int lane = tid & 63;

    const float rdx = rays_d[ray * 3 + 0], rdy = rays_d[ray * 3 + 1], rdz = rays_d[ray * 3 + 2];
    const float inv = rsqrtf(rdx * rdx + rdy * rdy + rdz * rdz);
    const float dx = rdx * inv, dy = rdy * inv, dz = rdz * inv;
    const float ox = rays_o[ray * 3 + 0], oy = rays_o[ray * 3 + 1], oz = rays_o[ray * 3 + 2];
    if (lane == 0) {
      g_dir[ray * 3 + 0] = dx; g_dir[ray * 3 + 1] = dy; g_dir[ray * 3 + 2] = dz;
    }

    const int s0 = lane * 2, s1 = s0 + 1;
    bool in0, in1;
    const float al0 = sample_alpha(dgrid, ox, oy, oz, dx, dy, dz, s0, in0);
    const float al1 = sample_alpha(dgrid, ox, oy, oz, dx, dy, dz, s1, in1);

    const float p0 = 1.0f - al0 + 1e-10f;
    const float p1 = 1.0f - al1 + 1e-10f;
    float incl = p0 * p1;
#pragma unroll
    for (int off = 1; off < 64; off <<= 1) {
      float v = __shfl_up(incl, off);
      if (lane >= off) incl *= v;
    }
    float excl = __shfl_up(incl, 1);
    if (lane == 0) excl = 1.0f;
    const float w0 = al0 * excl;
    const float w1 = al1 * excl * p0;

    float acc  = w0 + w1;
    float woob = (in0 ? 0.0f : w0) + (in1 ? 0.0f : w1);
#pragma unroll
    for (int off = 32; off > 0; off >>= 1) {
      acc  += __shfl_xor(acc, off);
      woob += __shfl_xor(woob, off);
    }

    const unsigned long long m0 = __ballot(in0);
    const unsigned long long m1 = __ballot(in1);
    const int n_in = (int)__popcll(m0) + (int)__popcll(m1);

    if (lane == 0) {
      g_woob[ray] = woob;
      g_cnt[ray]  = (n_in > MAXP) ? MAXP : n_in;
    }
    if (lane < 3) out[ray * 3 + lane] = 1.0f - acc;   // K2 atomically adds onto this

    const unsigned long long low = (1ull << lane) - 1ull;
    const int r0 = (int)__popcll(m0 & low) + (int)__popcll(m1 & low);
    if (in0 && r0 < MAXP) {
      g_sidx[ray * MAXP + r0] = (unsigned char)s0;
      g_w[ray * MAXP + r0]    = w0;
    }
    if (in1) {
      const int r1 = r0 + (in0 ? 1 : 0);
      if (r1 < MAXP) {
        g_sidx[ray * MAXP + r1] = (unsigned char)s1;
        g_w[ray * MAXP + r1]    = w1;
      }
    }
    return;
  }

  // ---- base: 16 rays per block -> g_hbase + g_rgboob (independent of prep) ----
  __shared__ float s_in[39][TILE];   // rows 0-2 vd; 3-20 sin(vd); 21-38 cos(vd)
  __shared__ float s_h1[FC][20];
  __shared__ float s_h2[FC][20];
  __shared__ float s_bc[FC], s_ps[FC];

  const int r0 = (bid - 512) * 16;
  if (tid < 16) {
    const int j = tid;
    const float rdx = rays_d[(r0 + j) * 3 + 0], rdy = rays_d[(r0 + j) * 3 + 1],
                rdz = rays_d[(r0 + j) * 3 + 2];
    const float inv = rsqrtf(rdx * rdx + rdy * rdy + rdz * rdz);
    s_in[0][j] = rdx * inv;
    s_in[1][j] = rdy * inv;
    s_in[2][j] = rdz * inv;
  }
  {  // cos(0)-block column sums, two interleaved halves (no dep on s_in)
    const int nrn = tid & 127, h = tid >> 7;
    float v = 0.0f;
#pragma unroll 9
    for (int k = 192 + h; k < 354; k += 2) v += W1[k * FC + nrn];
    if (h) s_ps[nrn] = v; else s_bc[nrn] = v;
  }
  __syncthreads();
  for (int a = tid; a < 18 * TILE; a += 256) {
    const int j = a & 15, idx = a >> 4, d = idx / 6, f = idx % 6;
    float sn, cs; __sincosf(s_in[d][j] * (float)(1 << f), &sn, &cs);
    s_in[3 + idx][j]  = sn;
    s_in[21 + idx][j] = cs;
  }
  __syncthreads();

  const int nrn = tid & 127;
  const int j0  = (tid >> 7) * 8;

  float a1[8];
  {
    const float bb = b1[nrn];
#pragma unroll
    for (int i = 0; i < 8; ++i) a1[i] = bb;
  }
#pragma unroll
  for (int r = 0; r < 39; ++r) {
    const int k = (r < 3) ? (27 + r) : (351 + r);
    const float wv = W1[k * FC + nrn];
    const float4 v0 = *(const float4*)&s_in[r][j0];
    const float4 v1 = *(const float4*)&s_in[r][j0 + 4];
    a1[0] = fmaf(v0.x, wv, a1[0]); a1[1] = fmaf(v0.y, wv, a1[1]);
    a1[2] = fmaf(v0.z, wv, a1[2]); a1[3] = fmaf(v0.w, wv, a1[3]);
    a1[4] = fmaf(v1.x, wv, a1[4]); a1[5] = fmaf(v1.y, wv, a1[5]);
    a1[6] = fmaf(v1.z, wv, a1[6]); a1[7] = fmaf(v1.w, wv, a1[7]);
  }
  const float bcv = s_bc[nrn] + s_ps[nrn];
#pragma unroll
  for (int i = 0; i < 8; ++i) {
    g_hbase[(size_t)(r0 + j0 + i) * FC + nrn] = a1[i];
    s_h1[nrn][j0 + i] = fmaxf(a1[i] + bcv, 0.0f);
  }
  __syncthreads();

  float a2[8];
  {
    const float bb = b2[nrn];
#pragma unroll
    for (int i = 0; i < 8; ++i) a2[i] = bb;
  }
#pragma unroll 4
  for (int k = 0; k < FC; ++k) {
    const float wv = W2[k * FC + nrn];
    const float4 u0 = *(const float4*)&s_h1[k][j0];
    const float4 u1 = *(const float4*)&s_h1[k][j0 + 4];
    a2[0] = fmaf(u0.x, wv, a2[0]); a2[1] = fmaf(u0.y, wv, a2[1]);
    a2[2] = fmaf(u0.z, wv, a2[2]); a2[3] = fmaf(u0.w, wv, a2[3]);
    a2[4] = fmaf(u1.x, wv, a2[4]); a2[5] = fmaf(u1.y, wv, a2[5]);
    a2[6] = fmaf(u1.z, wv, a2[6]); a2[7] = fmaf(u1.w, wv, a2[7]);
  }
#pragma unroll
  for (int i = 0; i < 8; ++i) s_h2[nrn][j0 + i] = fmaxf(a2[i], 0.0f);
  __syncthreads();

  if (tid < 48) {
    const int j = tid / 3, c = tid - j * 3;
    float a3 = b3[c];
#pragma unroll 8
    for (int k = 0; k < FC; ++k)
      a3 = fmaf(s_h2[k][j], W3[k * 3 + c], a3);
    g_rgboob[(r0 + j) * 3 + c] = 1.0f / (1.0f + __expf(-a3));
  }
}

// ---------------- K2: per-block prefix over g_cnt + OOB composite + item MLP ----------------
__global__ __launch_bounds__(256) void k_items(const float* __restrict__ rays_o,
                                               const float* __restrict__ g_dir,
                                               const float* __restrict__ agrid,
                                               const float* __restrict__ W1,
                                               const float* __restrict__ W2,
                                               const float* __restrict__ W3,
                                               const float* __restrict__ b2,
                                               const float* __restrict__ b3,
                                               const float* __restrict__ g_hbase,
                                               const float* __restrict__ g_woob,
                                               const float* __restrict__ g_rgboob,
                                               const int* __restrict__ g_cnt,
                                               const unsigned char* __restrict__ g_sidx,
                                               const float* __restrict__ g_w,
                                               float* __restrict__ out) {
  const int tid = threadIdx.x;
  __shared__ int   s_pfx[NRAYS + 1];  // 8196 B, persists across tiles
  __shared__ int   s_wt[4];
  __shared__ float s_inT[R1][TILE];   // 22.5 KB; tail-reused as h2 [128][20]
  __shared__ float s_hT[FC][20];      // 10 KB
  __shared__ int   s_rayid[TILE];
  __shared__ float s_jw[TILE], s_gx[TILE], s_gy[TILE], s_gz[TILE];
  __shared__ int   s_vld[TILE];

  // ---- exclusive prefix sum of per-ray item counts (exact ints) ----
  {
    const int b0 = tid * 8;
    const int4 ca = *(const int4*)&g_cnt[b0];
    const int4 cb = *(const int4*)&g_cnt[b0 + 4];
    int c8[8] = {ca.x, ca.y, ca.z, ca.w, cb.x, cb.y, cb.z, cb.w};
    int ex[8], run = 0;
#pragma unroll
    for (int i = 0; i < 8; ++i) { ex[i] = run; run += c8[i]; }
    int inclv = run;
    const int lane = tid & 63;
#pragma unroll
    for (int off = 1; off < 64; off <<= 1) {
      int v = __shfl_up(inclv, off);
      if (lane >= off) inclv += v;
    }
    if (lane == 63) s_wt[tid >> 6] = inclv;
    __syncthreads();
    int woff = 0;
    const int wq = tid >> 6;
    if (wq > 0) woff += s_wt[0];
    if (wq > 1) woff += s_wt[1];
    if (wq > 2) woff += s_wt[2];
    const int tbase = woff + inclv - run;
#pragma unroll
    for (int i = 0; i < 8; ++i) s_pfx[b0 + i] = tbase + ex[i];
    if (tid == 255) s_pfx[NRAYS] = tbase + run;
  }
  __syncthreads();
  const int total  = s_pfx[NRAYS];
  const int ntiles = 8 + ((total + TILE - 1) >> 4);

  for (int tile = blockIdx.x; tile < ntiles; tile += gridDim.x) {
    if (tile < 8) {   // OOB composite (block-uniform branch, no barriers inside)
      const int ray = tile * 256 + tid;
      const float wv = g_woob[ray];
#pragma unroll
      for (int c = 0; c < 3; ++c)
        atomicAdd(&out[ray * 3 + c], wv * g_rgboob[ray * 3 + c]);
      continue;
    }
    const int it = tile - 8;

    if (tid < TILE) {
      const int gi  = it * TILE + tid;
      const int vld = gi < total;
      int ray = 0, s = 0;
      float wj = 0.0f;
      if (vld) {
        int lo = 0, hi = NRAYS - 1;
        while (lo < hi) {
          const int mid = (lo + hi + 1) >> 1;
          if (s_pfx[mid] <= gi) lo = mid; else hi = mid - 1;
        }
        ray = lo;
        const int slot = gi - s_pfx[ray];
        s  = g_sidx[ray * MAXP + slot];
        wj = g_w[ray * MAXP + slot];
      }
      s_rayid[tid] = ray;
      s_vld[tid]   = vld;
      s_jw[tid]    = wj;
      const float dxx = g_dir[ray * 3 + 0], dyy = g_dir[ray * 3 + 1], dzz = g_dir[ray * 3 + 2];
      const float t = 2.0f + (4.0f / 127.0f) * (float)s;
      s_gx[tid] = ((rays_o[ray * 3 + 0] + dxx * t) * (2.0f / 3.0f) + 1.0f) * 63.5f;
      s_gy[tid] = ((rays_o[ray * 3 + 1] + dyy * t) * (2.0f / 3.0f) + 1.0f) * 63.5f;
      s_gz[tid] = ((rays_o[ray * 3 + 2] + dzz * t) * (2.0f / 3.0f) + 1.0f) * 63.5f;
    }
    __syncthreads();

    for (int a = tid; a < APPC * TILE; a += 256) {
      const int j = a & (TILE - 1), c = a >> 4;
      s_inT[c][j] = s_vld[j]
                        ? tri_sample(agrid + (size_t)c * G * G * G, s_gx[j], s_gy[j], s_gz[j])
                        : 0.0f;
    }
    __syncthreads();

    for (int a = tid; a < 162 * TILE; a += 256) {
      const int j = a & (TILE - 1), idx = a >> 4;
      const int d = idx / 6, f = idx % 6;
      float sn, cs; __sincosf(s_inT[d][j] * (float)(1 << f), &sn, &cs);
      s_inT[27 + idx][j]  = sn;
      s_inT[189 + idx][j] = cs;
    }
    __syncthreads();

    const int nrn = tid & 127;
    const int j0  = (tid >> 7) * 8;

    float a1[8];
#pragma unroll
    for (int i = 0; i < 8; ++i)
      a1[i] = g_hbase[(size_t)s_rayid[j0 + i] * FC + nrn];

    const float* w1p = W1 + nrn;
#pragma unroll 9
    for (int r = 0; r < 27; ++r) {
      const float wv = w1p[r * FC];
      const float4 v0 = *(const float4*)&s_inT[r][j0];
      const float4 v1 = *(const float4*)&s_inT[r][j0 + 4];
      a1[0] = fmaf(v0.x, wv, a1[0]); a1[1] = fmaf(v0.y, wv, a1[1]);
      a1[2] = fmaf(v0.z, wv, a1[2]); a1[3] = fmaf(v0.w, wv, a1[3]);
      a1[4] = fmaf(v1.x, wv, a1[4]); a1[5] = fmaf(v1.y, wv, a1[5]);
      a1[6] = fmaf(v1.z, wv, a1[6]); a1[7] = fmaf(v1.w, wv, a1[7]);
    }
#pragma unroll 8
    for (int r = 27; r < R1; ++r) {
      const float wv = w1p[(r + 3) * FC];
      const float4 v0 = *(const float4*)&s_inT[r][j0];
      const float4 v1 = *(const float4*)&s_inT[r][j0 + 4];
      a1[0] = fmaf(v0.x, wv, a1[0]); a1[1] = fmaf(v0.y, wv, a1[1]);
      a1[2] = fmaf(v0.z, wv, a1[2]); a1[3] = fmaf(v0.w, wv, a1[3]);
      a1[4] = fmaf(v1.x, wv, a1[4]); a1[5] = fmaf(v1.y, wv, a1[5]);
      a1[6] = fmaf(v1.z, wv, a1[6]); a1[7] = fmaf(v1.w, wv, a1[7]);
    }
#pragma unroll
    for (int i = 0; i < 8; ++i) s_hT[nrn][j0 + i] = fmaxf(a1[i], 0.0f);
    __syncthreads();

    float a2[8];
    {
      const float bb = b2[nrn];
#pragma unroll
      for (int i = 0; i < 8; ++i) a2[i] = bb;
    }
#pragma unroll 4
    for (int k = 0; k < FC; ++k) {
      const float wv = W2[k * FC + nrn];
      const float4 u0 = *(const float4*)&s_hT[k][j0];
      const float4 u1 = *(const float4*)&s_hT[k][j0 + 4];
      a2[0] = fmaf(u0.x, wv, a2[0]); a2[1] = fmaf(u0.y, wv, a2[1]);
      a2[2] = fmaf(u0.z, wv, a2[2]); a2[3] = fmaf(u0.w, wv, a2[3]);
      a2[4] = fmaf(u1.x, wv, a2[4]); a2[5] = fmaf(u1.y, wv, a2[5]);
      a2[6] = fmaf(u1.z, wv, a2[6]); a2[7] = fmaf(u1.w, wv, a2[7]);
    }
    float* s_h2 = &s_inT[0][0];  // reuse as [128][20]; all s_inT reads finished pre-barrier
#pragma unroll
    for (int i = 0; i < 8; ++i) s_h2[nrn * 20 + j0 + i] = fmaxf(a2[i], 0.0f);
    __syncthreads();

    if (tid < 3 * TILE) {
      const int j = tid / 3, c = tid - j * 3;
      if (s_vld[j] && s_jw[j] != 0.0f) {
        float a3 = b3[c];
#pragma unroll 8
        for (int k = 0; k < FC; ++k)
          a3 = fmaf(s_h2[k * 20 + j], W3[k * 3 + c], a3);
        const float rgb = 1.0f / (1.0f + __expf(-a3));
        atomicAdd(&out[s_rayid[j] * 3 + c], s_jw[j] * rgb);
      }
    }
    __syncthreads();
  }
}

extern "C" void kernel_launch(void* const* d_in, const int* in_sizes, int n_in,
                              void* d_out, int out_size, void* d_ws, size_t ws_size,
                              hipStream_t stream) {
  const float* rays_o = (const float*)d_in[0];
  const float* rays_d = (const float*)d_in[1];
  const float* dgrid  = (const float*)d_in[2];
  const float* agrid  = (const float*)d_in[3];
  const float* W1     = (const float*)d_in[4];
  const float* b1     = (const float*)d_in[5];
  const float* W2     = (const float*)d_in[6];
  const float* b2     = (const float*)d_in[7];
  const float* W3     = (const float*)d_in[8];
  const float* b3     = (const float*)d_in[9];
  float* out = (float*)d_out;

  char* ws = (char*)d_ws;
  float*         g_dir    = (float*)(ws);                 // 24 KB
  float*         g_woob   = (float*)(ws + 24576);         // 8 KB
  float*         g_rgboob = (float*)(ws + 32768);         // 24 KB
  int*           g_cnt    = (int*)(ws + 57344);           // 8 KB
  float*         g_hbase  = (float*)(ws + 65536);         // 1 MB
  float*         g_w      = (float*)(ws + 65536 + 1048576);          // 384 KB
  unsigned char* g_sidx   = (unsigned char*)(ws + 65536 + 1048576 + 393216);  // 96 KB

  hipLaunchKernelGGL(k_phase1, dim3(640), dim3(256), 0, stream,
                     rays_o, rays_d, dgrid, W1, W2, W3, b1, b2, b3,
                     out, g_dir, g_woob, g_hbase, g_rgboob, g_cnt, g_sidx, g_w);
  hipLaunchKernelGGL(k_items, dim3(768), dim3(256), 0, stream,
                     rays_o, g_dir, agrid, W1, W2, W3, b2, b3,
                     g_hbase, g_woob, g_rgboob, g_cnt, g_sidx, g_w, out);
}

// Round 9
// 58.983 us; speedup vs baseline: 1.8430x; 1.0640x over previous
//
#include <hip/hip_runtime.h>

#define NRAYS 2048
#define NS    128
#define G     128
#define FC    128
#define APPC  27
#define TILE  8
#define MAXP  48    // max in-bounds samples per ray (geometric bound ~24)
#define R1    351   // compact item rows: 27 feats + 162 sin + 162 cos; W1 row k = r<27 ? r : r+3

static __device__ __forceinline__ float tri_sample(const float* __restrict__ vol,
                                                   float gx, float gy, float gz) {
  int x0 = (int)gx; x0 = x0 < 0 ? 0 : (x0 > G - 2 ? G - 2 : x0);
  int y0 = (int)gy; y0 = y0 < 0 ? 0 : (y0 > G - 2 ? G - 2 : y0);
  int z0 = (int)gz; z0 = z0 < 0 ? 0 : (z0 > G - 2 ? G - 2 : z0);
  float fx = gx - (float)x0;
  float fy = gy - (float)y0;
  float fz = gz - (float)z0;
  const float* p = vol + ((z0 * G + y0) * G + x0);
  float v000 = p[0], v001 = p[1];
  float v010 = p[G], v011 = p[G + 1];
  const float* q = p + G * G;
  float v100 = q[0], v101 = q[1];
  float v110 = q[G], v111 = q[G + 1];
  float c00 = v000 + (v001 - v000) * fx;
  float c01 = v010 + (v011 - v010) * fx;
  float c10 = v100 + (v101 - v100) * fx;
  float c11 = v110 + (v111 - v110) * fx;
  float c0  = c00 + (c01 - c00) * fy;
  float c1  = c10 + (c11 - c10) * fy;
  return c0 + (c1 - c0) * fz;
}

// softplus(x) for x <= ~-5: log1p(e^x) = e^x - e^x^2/2 + O(e^3x); abs error < 1e-8
static __device__ __forceinline__ float sample_alpha(const float* __restrict__ dgrid,
                                                     float ox, float oy, float oz,
                                                     float dx, float dy, float dz,
                                                     int s, bool& inb) {
  const float t  = 2.0f + (4.0f / 127.0f) * (float)s;
  const float px = (ox + dx * t) * (2.0f / 3.0f);
  const float py = (oy + dy * t) * (2.0f / 3.0f);
  const float pz = (oz + dz * t) * (2.0f / 3.0f);
  inb = (fabsf(px) <= 1.0f) && (fabsf(py) <= 1.0f) && (fabsf(pz) <= 1.0f);
  float sf = 0.0f;
  if (inb)
    sf = tri_sample(dgrid, (px + 1.0f) * 63.5f, (py + 1.0f) * 63.5f, (pz + 1.0f) * 63.5f);
  const float y  = __expf(sf - 10.0f);          // <= ~7e-3 always
  const float sp = y - 0.5f * y * y;            // softplus(sf-10) to ~1e-9
  return 1.0f - __expf(-sp * 0.78125f);
}

// ---------------- K1: prep (blocks 0-511, wave/ray) || base (blocks 512-767, 8 rays each) ----------------
__global__ __launch_bounds__(256) void k_phase1(
    const float* __restrict__ rays_o, const float* __restrict__ rays_d,
    const float* __restrict__ dgrid,
    const float* __restrict__ W1, const float* __restrict__ W2,
    const float* __restrict__ W3, const float* __restrict__ b1,
    const float* __restrict__ b2, const float* __restrict__ b3,
    float* __restrict__ out, float* __restrict__ g_dir,
    float* __restrict__ g_woob, float* __restrict__ g_hbase,
    float* __restrict__ g_rgboob, unsigned char* __restrict__ g_cnt8,
    unsigned char* __restrict__ g_sidx, float* __restrict__ g_w) {
  const int bid = blockIdx.x;
  const int tid = threadIdx.x;

  if (bid < 512) {
    // ---- prep: one wave per ray; fixed per-ray slots, no atomics ----
    const int ray  = bid * 4 + (tid >> 6);
    const int lane = tid & 63;

    const float rdx = rays_d[ray * 3 + 0], rdy = rays_d[ray * 3 + 1], rdz = rays_d[ray * 3 + 2];
    const float inv = rsqrtf(rdx * rdx + rdy * rdy + rdz * rdz);
    const float dx = rdx * inv, dy = rdy * inv, dz = rdz * inv;
    const float ox = rays_o[ray * 3 + 0], oy = rays_o[ray * 3 + 1], oz = rays_o[ray * 3 + 2];
    if (lane == 0) {
      g_dir[ray * 3 + 0] = dx; g_dir[ray * 3 + 1] = dy; g_dir[ray * 3 + 2] = dz;
    }

    const int s0 = lane * 2, s1 = s0 + 1;
    bool in0, in1;
    const float al0 = sample_alpha(dgrid, ox, oy, oz, dx, dy, dz, s0, in0);
    const float al1 = sample_alpha(dgrid, ox, oy, oz, dx, dy, dz, s1, in1);

    const float p0 = 1.0f - al0 + 1e-10f;
    const float p1 = 1.0f - al1 + 1e-10f;
    float incl = p0 * p1;
#pragma unroll
    for (int off = 1; off < 64; off <<= 1) {
      float v = __shfl_up(incl, off);
      if (lane >= off) incl *= v;
    }
    float excl = __shfl_up(incl, 1);
    if (lane == 0) excl = 1.0f;
    const float w0 = al0 * excl;
    const float w1 = al1 * excl * p0;

    float acc  = w0 + w1;
    float woob = (in0 ? 0.0f : w0) + (in1 ? 0.0f : w1);
#pragma unroll
    for (int off = 32; off > 0; off >>= 1) {
      acc  += __shfl_xor(acc, off);
      woob += __shfl_xor(woob, off);
    }

    const unsigned long long m0 = __ballot(in0);
    const unsigned long long m1 = __ballot(in1);
    const int n_in = (int)__popcll(m0) + (int)__popcll(m1);

    if (lane == 0) {
      g_woob[ray] = woob;
      g_cnt8[ray] = (unsigned char)((n_in > MAXP) ? MAXP : n_in);
    }
    if (lane < 3) out[ray * 3 + lane] = 1.0f - acc;   // K2 atomically adds onto this

    const unsigned long long low = (1ull << lane) - 1ull;
    const int r0 = (int)__popcll(m0 & low) + (int)__popcll(m1 & low);
    if (in0 && r0 < MAXP) {
      g_sidx[ray * MAXP + r0] = (unsigned char)s0;
      g_w[ray * MAXP + r0]    = w0;
    }
    if (in1) {
      const int r1 = r0 + (in0 ? 1 : 0);
      if (r1 < MAXP) {
        g_sidx[ray * MAXP + r1] = (unsigned char)s1;
        g_w[ray * MAXP + r1]    = w1;
      }
    }
    return;
  }

  // ---- base: 8 rays per block (256 blocks) -> g_hbase + g_rgboob ----
  __shared__ float s_in[39][8];      // rows 0-2 vd; 3-20 sin(vd); 21-38 cos(vd)
  __shared__ float s_h1[FC][12];
  __shared__ float s_h2[FC][12];
  __shared__ float s_bc[FC], s_ps[FC];

  const int r0 = (bid - 512) * 8;
  if (tid < 24) {
    const int j = tid & 7, d = tid >> 3;
    const float rdx = rays_d[(r0 + j) * 3 + 0], rdy = rays_d[(r0 + j) * 3 + 1],
                rdz = rays_d[(r0 + j) * 3 + 2];
    const float inv = rsqrtf(rdx * rdx + rdy * rdy + rdz * rdz);
    s_in[d][j] = (d == 0) ? rdx * inv : ((d == 1) ? rdy * inv : rdz * inv);
  }
  {  // cos(0)-block column sums, two interleaved halves (no dep on s_in)
    const int nrn = tid & 127, h = tid >> 7;
    float v = 0.0f;
#pragma unroll 9
    for (int k = 192 + h; k < 354; k += 2) v += W1[k * FC + nrn];
    if (h) s_ps[nrn] = v; else s_bc[nrn] = v;
  }
  __syncthreads();
  for (int a = tid; a < 18 * 8; a += 256) {
    const int j = a & 7, idx = a >> 3, d = idx / 6, f = idx % 6;
    float sn, cs; __sincosf(s_in[d][j] * (float)(1 << f), &sn, &cs);
    s_in[3 + idx][j]  = sn;
    s_in[21 + idx][j] = cs;
  }
  __syncthreads();

  const int nrn = tid & 127;
  const int j0  = (tid >> 7) * 4;

  float a1[4];
  {
    const float bb = b1[nrn];
#pragma unroll
    for (int i = 0; i < 4; ++i) a1[i] = bb;
  }
#pragma unroll
  for (int r = 0; r < 39; ++r) {
    const int k = (r < 3) ? (27 + r) : (351 + r);
    const float wv = W1[k * FC + nrn];
    const float4 v0 = *(const float4*)&s_in[r][j0];
    a1[0] = fmaf(v0.x, wv, a1[0]); a1[1] = fmaf(v0.y, wv, a1[1]);
    a1[2] = fmaf(v0.z, wv, a1[2]); a1[3] = fmaf(v0.w, wv, a1[3]);
  }
  const float bcv = s_bc[nrn] + s_ps[nrn];
#pragma unroll
  for (int i = 0; i < 4; ++i) {
    g_hbase[(size_t)(r0 + j0 + i) * FC + nrn] = a1[i];
    s_h1[nrn][j0 + i] = fmaxf(a1[i] + bcv, 0.0f);
  }
  __syncthreads();

  float a2[4];
  {
    const float bb = b2[nrn];
#pragma unroll
    for (int i = 0; i < 4; ++i) a2[i] = bb;
  }
#pragma unroll 4
  for (int k = 0; k < FC; ++k) {
    const float wv = W2[k * FC + nrn];
    const float4 u0 = *(const float4*)&s_h1[k][j0];
    a2[0] = fmaf(u0.x, wv, a2[0]); a2[1] = fmaf(u0.y, wv, a2[1]);
    a2[2] = fmaf(u0.z, wv, a2[2]); a2[3] = fmaf(u0.w, wv, a2[3]);
  }
#pragma unroll
  for (int i = 0; i < 4; ++i) s_h2[nrn][j0 + i] = fmaxf(a2[i], 0.0f);
  __syncthreads();

  if (tid < 24) {
    const int j = tid / 3, c = tid - j * 3;
    float a3 = b3[c];
#pragma unroll 8
    for (int k = 0; k < FC; ++k)
      a3 = fmaf(s_h2[k][j], W3[k * 3 + c], a3);
    g_rgboob[(r0 + j) * 3 + c] = 1.0f / (1.0f + __expf(-a3));
  }
}

// ---------------- K2: per-block prefix over g_cnt8 + OOB composite + item MLP (TILE=8) ----------------
__global__ __launch_bounds__(256) void k_items(const float* __restrict__ rays_o,
                                               const float* __restrict__ g_dir,
                                               const float* __restrict__ agrid,
                                               const float* __restrict__ W1,
                                               const float* __restrict__ W2,
                                               const float* __restrict__ W3,
                                               const float* __restrict__ b2,
                                               const float* __restrict__ b3,
                                               const float* __restrict__ g_hbase,
                                               const float* __restrict__ g_woob,
                                               const float* __restrict__ g_rgboob,
                                               const unsigned char* __restrict__ g_cnt8,
                                               const unsigned char* __restrict__ g_sidx,
                                               const float* __restrict__ g_w,
                                               float* __restrict__ out) {
  const int tid = threadIdx.x;
  __shared__ int   s_pfx[NRAYS + 1];  // 8196 B, persists across tiles
  __shared__ int   s_wt[4];
  __shared__ float s_inT[R1][TILE];   // 11.2 KB; tail-reused as h2 [128][12]
  __shared__ float s_hT[FC][12];      // 6 KB
  __shared__ int   s_rayid[TILE];
  __shared__ float s_jw[TILE], s_gx[TILE], s_gy[TILE], s_gz[TILE];
  __shared__ int   s_vld[TILE];

  // ---- exclusive prefix sum of per-ray item counts (uchar, exact ints) ----
  {
    const int b0 = tid * 8;
    const uint2 cc = *(const uint2*)&g_cnt8[b0];
    int c8[8];
#pragma unroll
    for (int i = 0; i < 4; ++i) c8[i]     = (int)((cc.x >> (8 * i)) & 0xff);
#pragma unroll
    for (int i = 0; i < 4; ++i) c8[4 + i] = (int)((cc.y >> (8 * i)) & 0xff);
    int ex[8], run = 0;
#pragma unroll
    for (int i = 0; i < 8; ++i) { ex[i] = run; run += c8[i]; }
    int inclv = run;
    const int lane = tid & 63;
#pragma unroll
    for (int off = 1; off < 64; off <<= 1) {
      int v = __shfl_up(inclv, off);
      if (lane >= off) inclv += v;
    }
    if (lane == 63) s_wt[tid >> 6] = inclv;
    __syncthreads();
    int woff = 0;
    const int wq = tid >> 6;
    if (wq > 0) woff += s_wt[0];
    if (wq > 1) woff += s_wt[1];
    if (wq > 2) woff += s_wt[2];
    const int tbase = woff + inclv - run;
#pragma unroll
    for (int i = 0; i < 8; ++i) s_pfx[b0 + i] = tbase + ex[i];
    if (tid == 255) s_pfx[NRAYS] = tbase + run;
  }
  __syncthreads();
  const int total  = s_pfx[NRAYS];
  const int ntiles = 8 + ((total + TILE - 1) >> 3);

  for (int tile = blockIdx.x; tile < ntiles; tile += gridDim.x) {
    if (tile < 8) {   // OOB composite (block-uniform branch, no barriers inside)
      const int ray = tile * 256 + tid;
      const float wv = g_woob[ray];
#pragma unroll
      for (int c = 0; c < 3; ++c)
        atomicAdd(&out[ray * 3 + c], wv * g_rgboob[ray * 3 + c]);
      continue;
    }
    const int it = tile - 8;

    if (tid < TILE) {
      const int gi  = it * TILE + tid;
      const int vld = gi < total;
      int ray = 0, s = 0;
      float wj = 0.0f;
      if (vld) {
        int lo = 0, hi = NRAYS - 1;
        while (lo < hi) {
          const int mid = (lo + hi + 1) >> 1;
          if (s_pfx[mid] <= gi) lo = mid; else hi = mid - 1;
        }
        ray = lo;
        const int slot = gi - s_pfx[ray];
        s  = g_sidx[ray * MAXP + slot];
        wj = g_w[ray * MAXP + slot];
      }
      s_rayid[tid] = ray;
      s_vld[tid]   = vld;
      s_jw[tid]    = wj;
      const float dxx = g_dir[ray * 3 + 0], dyy = g_dir[ray * 3 + 1], dzz = g_dir[ray * 3 + 2];
      const float t = 2.0f + (4.0f / 127.0f) * (float)s;
      s_gx[tid] = ((rays_o[ray * 3 + 0] + dxx * t) * (2.0f / 3.0f) + 1.0f) * 63.5f;
      s_gy[tid] = ((rays_o[ray * 3 + 1] + dyy * t) * (2.0f / 3.0f) + 1.0f) * 63.5f;
      s_gz[tid] = ((rays_o[ray * 3 + 2] + dzz * t) * (2.0f / 3.0f) + 1.0f) * 63.5f;
    }
    __syncthreads();

    if (tid < APPC * TILE) {   // 216 work items
      const int j = tid & (TILE - 1), c = tid >> 3;
      s_inT[c][j] = s_vld[j]
                        ? tri_sample(agrid + (size_t)c * G * G * G, s_gx[j], s_gy[j], s_gz[j])
                        : 0.0f;
    }
    __syncthreads();

    for (int a = tid; a < 162 * TILE; a += 256) {
      const int j = a & (TILE - 1), idx = a >> 3;
      const int d = idx / 6, f = idx % 6;
      float sn, cs; __sincosf(s_inT[d][j] * (float)(1 << f), &sn, &cs);
      s_inT[27 + idx][j]  = sn;
      s_inT[189 + idx][j] = cs;
    }
    __syncthreads();

    const int nrn = tid & 127;
    const int j0  = (tid >> 7) * 4;

    float a1[4];
#pragma unroll
    for (int i = 0; i < 4; ++i)
      a1[i] = g_hbase[(size_t)s_rayid[j0 + i] * FC + nrn];

    const float* w1p = W1 + nrn;
#pragma unroll 9
    for (int r = 0; r < 27; ++r) {
      const float wv = w1p[r * FC];
      const float4 v0 = *(const float4*)&s_inT[r][j0];
      a1[0] = fmaf(v0.x, wv, a1[0]); a1[1] = fmaf(v0.y, wv, a1[1]);
      a1[2] = fmaf(v0.z, wv, a1[2]); a1[3] = fmaf(v0.w, wv, a1[3]);
    }
#pragma unroll 8
    for (int r = 27; r < R1; ++r) {
      const float wv = w1p[(r + 3) * FC];
      const float4 v0 = *(const float4*)&s_inT[r][j0];
      a1[0] = fmaf(v0.x, wv, a1[0]); a1[1] = fmaf(v0.y, wv, a1[1]);
      a1[2] = fmaf(v0.z, wv, a1[2]); a1[3] = fmaf(v0.w, wv, a1[3]);
    }
#pragma unroll
    for (int i = 0; i < 4; ++i) s_hT[nrn][j0 + i] = fmaxf(a1[i], 0.0f);
    __syncthreads();

    float a2[4];
    {
      const float bb = b2[nrn];
#pragma unroll
      for (int i = 0; i < 4; ++i) a2[i] = bb;
    }
#pragma unroll 4
    for (int k = 0; k < FC; ++k) {
      const float wv = W2[k * FC + nrn];
      const float4 u0 = *(const float4*)&s_hT[k][j0];
      a2[0] = fmaf(u0.x, wv, a2[0]); a2[1] = fmaf(u0.y, wv, a2[1]);
      a2[2] = fmaf(u0.z, wv, a2[2]); a2[3] = fmaf(u0.w, wv, a2[3]);
    }
    float* s_h2 = &s_inT[0][0];  // reuse as [128][12]; all s_inT reads finished pre-barrier
#pragma unroll
    for (int i = 0; i < 4; ++i) s_h2[nrn * 12 + j0 + i] = fmaxf(a2[i], 0.0f);
    __syncthreads();

    if (tid < 3 * TILE) {
      const int j = tid / 3, c = tid - j * 3;
      if (s_vld[j] && s_jw[j] != 0.0f) {
        float a3 = b3[c];
#pragma unroll 8
        for (int k = 0; k < FC; ++k)
          a3 = fmaf(s_h2[k * 12 + j], W3[k * 3 + c], a3);
        const float rgb = 1.0f / (1.0f + __expf(-a3));
        atomicAdd(&out[s_rayid[j] * 3 + c], s_jw[j] * rgb);
      }
    }
    __syncthreads();
  }
}

extern "C" void kernel_launch(void* const* d_in, const int* in_sizes, int n_in,
                              void* d_out, int out_size, void* d_ws, size_t ws_size,
                              hipStream_t stream) {
  const float* rays_o = (const float*)d_in[0];
  const float* rays_d = (const float*)d_in[1];
  const float* dgrid  = (const float*)d_in[2];
  const float* agrid  = (const float*)d_in[3];
  const float* W1     = (const float*)d_in[4];
  const float* b1     = (const float*)d_in[5];
  const float* W2     = (const float*)d_in[6];
  const float* b2     = (const float*)d_in[7];
  const float* W3     = (const float*)d_in[8];
  const float* b3     = (const float*)d_in[9];
  float* out = (float*)d_out;

  char* ws = (char*)d_ws;
  float*         g_dir    = (float*)(ws);                 // 24 KB
  float*         g_woob   = (float*)(ws + 24576);         // 8 KB
  float*         g_rgboob = (float*)(ws + 32768);         // 24 KB
  unsigned char* g_cnt8   = (unsigned char*)(ws + 57344); // 2 KB
  float*         g_hbase  = (float*)(ws + 65536);         // 1 MB
  float*         g_w      = (float*)(ws + 65536 + 1048576);                    // 384 KB
  unsigned char* g_sidx   = (unsigned char*)(ws + 65536 + 1048576 + 393216);   // 96 KB

  hipLaunchKernelGGL(k_phase1, dim3(768), dim3(256), 0, stream,
                     rays_o, rays_d, dgrid, W1, W2, W3, b1, b2, b3,
                     out, g_dir, g_woob, g_hbase, g_rgboob, g_cnt8, g_sidx, g_w);
  hipLaunchKernelGGL(k_items, dim3(768), dim3(256), 0, stream,
                     rays_o, g_dir, agrid, W1, W2, W3, b2, b3,
                     g_hbase, g_woob, g_rgboob, g_cnt8, g_sidx, g_w, out);
}